// Round 1
// 1210.144 us; speedup vs baseline: 1.3059x; 1.3059x over previous
//
#include <hip/hip_runtime.h>

// PointerNet: B=4, N=128, H=512, d_pair=256.
// Interface (verified over prior session):
//   inputs  f32, setup_inputs dict order
//   d_out   f32, 50,724,864 elements = [4][128][128][774]
// Per mlp g in {future(Wf1,Wf2,w3), hist1(Wh1a,Wh1b,wl1), hist2(Wh2a,Wh2b,wl2)}:
//   uv[m][c'] = sum_h P[m][h] * W1[(c'>=1024?512:0)+h][c'&1023]     (m = b*128+i)
//   y[bi,j,n] = relu( sum_k relu(uv[bi][k] + uv[bj][1024+k]) * W2[k][n] )
//   p = softmax_c( sum_n y[n] * w3[n][c] )
//   out[((bi)*128+j)*774 + g*258 + {n | 256+c}] = {y | p}
// Workspace: uv f32 [512][2048] = 4 MiB at ws+0 (reused per mlp);
//            W2F bf16 frag layout = 1 MiB at ws+4MiB (MFMA path only).
//
// R9 change: pair GEMM moved from f32 VALU (LDS-BW-bound, ~79 TB/s demand vs
// 69 TB/s ceiling, MfmaUtil=0) to split-bf16 3-product MFMA
// (zhi@whi + zlo@whi + zhi@wlo), which reconstructs f32 products to ~2^-16
// relative error. No LDS at all: A (z) fragments built in-register from uv,
// B (W2) fragments pre-laid-out in global by prep_w2.

typedef __attribute__((ext_vector_type(4))) float floatx4;
typedef __attribute__((ext_vector_type(2))) float floatx2;
typedef __attribute__((ext_vector_type(8))) short short8;

#define KT 16
#define LSTRIDE 68  // 64 + 4 pad (LDS bank-conflict break)

// ---------------------------------------------------------------------------
// Kernel 1: stage1 f32 GEMM (unchanged, proven). Block = 64m x 64c tile.
// ---------------------------------------------------------------------------
__global__ __launch_bounds__(256) void stage1_valu(
    const float* __restrict__ P,    // [512][512]
    const float* __restrict__ W1,   // [1024][1024], one mlp
    float* __restrict__ uv) {       // [512][2048]
  __shared__ float at[KT][LSTRIDE];  // at[k][m]
  __shared__ float wt[KT][LSTRIDE];  // wt[k][c]
  int bx = blockIdx.x;
  int m0 = (bx >> 5) * 64;
  int c0 = (bx & 31) * 64;
  int half = c0 >> 10;            // 0: u-half (W1 rows 0..511), 1: v-half
  int ccol = c0 & 1023;
  int tid = threadIdx.x;
  int tm = tid >> 4, tn = tid & 15;
  int lm = tid >> 2;              // 0..63  A-load row
  int lk4 = (tid & 3) * 4;        // A-load k chunk
  int lkk = tid >> 4;             // 0..15  W-load k row
  int lc4 = (tid & 15) * 4;       // W-load c chunk

  float acc[4][4] = {};

  for (int k0 = 0; k0 < 512; k0 += KT) {
    floatx4 pa = *(const floatx4*)(P + (long)(m0 + lm) * 512 + k0 + lk4);
    floatx4 wa = *(const floatx4*)(W1 + (long)(half * 512 + k0 + lkk) * 1024 + ccol + lc4);
    __syncthreads();              // prev-iter LDS reads done
#pragma unroll
    for (int e = 0; e < 4; e++) at[lk4 + e][lm] = pa[e];
    *(floatx4*)&wt[lkk][lc4] = wa;
    __syncthreads();
#pragma unroll
    for (int kk = 0; kk < KT; kk++) {
      floatx4 av = *(const floatx4*)&at[kk][tm * 4];
      floatx4 wv = *(const floatx4*)&wt[kk][tn * 4];
#pragma unroll
      for (int mm = 0; mm < 4; mm++)
#pragma unroll
        for (int nn = 0; nn < 4; nn++)
          acc[mm][nn] += av[mm] * wv[nn];
    }
  }
#pragma unroll
  for (int mm = 0; mm < 4; mm++) {
    floatx4 o;
#pragma unroll
    for (int nn = 0; nn < 4; nn++) o[nn] = acc[mm][nn];
    *(floatx4*)(uv + (long)(m0 + tm * 4 + mm) * 2048 + c0 + tn * 4) = o;
  }
}

// ---------------------------------------------------------------------------
// Kernel 1b: W2 -> MFMA B-fragment layout, split-bf16 (truncated hi, lo).
// W2F[kt(32)][nf(16)][hl(2)][lane(64)][e(8)] bf16-as-u16; 1 MiB.
// lane = 16g + c holds W2[kt*32 + g*8 + e][nf*16 + c]  (same slot->k map as A).
// ---------------------------------------------------------------------------
__global__ __launch_bounds__(256) void prep_w2(
    const float* __restrict__ W2,          // [1024][256]
    unsigned short* __restrict__ W2F) {
  int t = blockIdx.x * 256 + threadIdx.x;  // 32768 threads total
  int lane = t & 63;
  int nf = (t >> 6) & 15;
  int kt = t >> 10;                        // 0..31
  int g = lane >> 4, c = lane & 15;
  int n = nf * 16 + c;
  int kbase = kt * 32 + g * 8;

  union U { unsigned u[4]; short8 s; };
  U H, L;
  unsigned hb[8], lb[8];
#pragma unroll
  for (int e = 0; e < 8; e++) {
    float w = W2[(long)(kbase + e) * 256 + n];
    unsigned wb = __float_as_uint(w);
    unsigned h = wb & 0xFFFF0000u;
    float l = w - __uint_as_float(h);       // exact
    hb[e] = h;
    lb[e] = __float_as_uint(l) & 0xFFFF0000u;
  }
#pragma unroll
  for (int p = 0; p < 4; p++) {
    H.u[p] = __builtin_amdgcn_perm(hb[2 * p + 1], hb[2 * p], 0x07060302u);
    L.u[p] = __builtin_amdgcn_perm(lb[2 * p + 1], lb[2 * p], 0x07060302u);
  }
  long base = (((long)kt * 16 + nf) * 2) * 64 + lane;
  *(short8*)(W2F + (base + 0) * 8) = H.s;
  *(short8*)(W2F + (base + 64) * 8) = L.s;   // hl=1 slot
}

// ---------------------------------------------------------------------------
// Kernel 2 (hot): pair GEMM via split-bf16 MFMA. One block per bi; 4 waves,
// wave w owns j rows [w*32, w*32+32), all 256 n columns (16 n-frags).
// acc = zhi@whi + zlo@whi + zhi@wlo accumulated in f32 AGPRs. No LDS.
// ---------------------------------------------------------------------------
__device__ __forceinline__ void make_frag(
    const floatx4& ua, const floatx4& ub,
    const floatx4& va, const floatx4& vb,
    short8& hi, short8& lo) {
  unsigned hb[8], lb[8];
#pragma unroll
  for (int e = 0; e < 8; e++) {
    float z = (e < 4) ? (ua[e] + va[e]) : (ub[e - 4] + vb[e - 4]);
    z = fmaxf(z, 0.0f);
    unsigned zb = __float_as_uint(z);
    unsigned h = zb & 0xFFFF0000u;
    float l = z - __uint_as_float(h);       // exact remainder
    hb[e] = h;
    lb[e] = __float_as_uint(l) & 0xFFFF0000u;
  }
  union U { unsigned u[4]; short8 s; };
  U H, L;
#pragma unroll
  for (int p = 0; p < 4; p++) {
    H.u[p] = __builtin_amdgcn_perm(hb[2 * p + 1], hb[2 * p], 0x07060302u);
    L.u[p] = __builtin_amdgcn_perm(lb[2 * p + 1], lb[2 * p], 0x07060302u);
  }
  hi = H.s;
  lo = L.s;
}

__global__ __launch_bounds__(256, 2) void pair_mfma(
    const float* __restrict__ uv,           // [512][2048]
    const unsigned short* __restrict__ W2F, // frag layout, 1 MiB
    float* __restrict__ out, int mlp) {
  int bi = blockIdx.x;          // 0..511 = b*128 + i
  int b = bi >> 7;
  int tid = threadIdx.x;
  int wid = tid >> 6;           // wave 0..3 -> j rows [wid*32, wid*32+32)
  int lane = tid & 63;
  int g = lane >> 4;            // k-chunk selector
  int r = lane & 15;            // A row within 16-tile / D col within 16-tile
  int wj = wid * 32;

  const float* ubase = uv + (long)bi * 2048;                          // u[k]
  const float* v0 = uv + (long)(b * 128 + wj + r) * 2048 + 1024;      // rows wj+r
  const float* v1 = v0 + 16 * 2048;                                   // rows wj+16+r

  floatx4 acc[2][16];
#pragma unroll
  for (int mm = 0; mm < 2; mm++)
#pragma unroll
    for (int nf = 0; nf < 16; nf++) acc[mm][nf] = (floatx4){0.f, 0.f, 0.f, 0.f};

  for (int kt = 0; kt < 32; kt++) {
    int k0 = kt * 32 + g * 8;
    floatx4 u0 = *(const floatx4*)(ubase + k0);
    floatx4 u1 = *(const floatx4*)(ubase + k0 + 4);
    floatx4 va0 = *(const floatx4*)(v0 + k0);
    floatx4 va1 = *(const floatx4*)(v0 + k0 + 4);
    floatx4 vb0 = *(const floatx4*)(v1 + k0);
    floatx4 vb1 = *(const floatx4*)(v1 + k0 + 4);

    short8 ahi[2], alo[2];
    make_frag(u0, u1, va0, va1, ahi[0], alo[0]);
    make_frag(u0, u1, vb0, vb1, ahi[1], alo[1]);

    const short8* wf = (const short8*)W2F + ((long)kt * 16 * 2) * 64 + lane;
#pragma unroll
    for (int nf = 0; nf < 16; nf++) {
      short8 whi = wf[(nf * 2 + 0) * 64];
      short8 wlo = wf[(nf * 2 + 1) * 64];
#pragma unroll
      for (int mm = 0; mm < 2; mm++) {
        acc[mm][nf] = __builtin_amdgcn_mfma_f32_16x16x32_bf16(
            ahi[mm], whi, acc[mm][nf], 0, 0, 0);
        acc[mm][nf] = __builtin_amdgcn_mfma_f32_16x16x32_bf16(
            alo[mm], whi, acc[mm][nf], 0, 0, 0);
        acc[mm][nf] = __builtin_amdgcn_mfma_f32_16x16x32_bf16(
            ahi[mm], wlo, acc[mm][nf], 0, 0, 0);
      }
    }
  }

  // Epilogue: D layout col = lane&15 (n), row = (lane>>4)*4 + reg (j).
  float* ob = out + (long)(bi * 128) * 774 + mlp * 258;
#pragma unroll
  for (int mm = 0; mm < 2; mm++) {
#pragma unroll
    for (int nf = 0; nf < 16; nf++) {
      int n = nf * 16 + r;
      int jrow = wj + mm * 16 + g * 4;
#pragma unroll
      for (int reg = 0; reg < 4; reg++) {
        float y = acc[mm][nf][reg];
        ob[(long)(jrow + reg) * 774 + n] = y > 0.f ? y : 0.f;
      }
    }
  }
}

// ---------------------------------------------------------------------------
// Kernel 2-fallback: original f32 VALU pair GEMM (used only if ws too small).
// ---------------------------------------------------------------------------
__global__ __launch_bounds__(256) void pair_valu(
    const float* __restrict__ uv,   // [512][2048], this mlp
    const float* __restrict__ W2,   // [1024][256], this mlp
    float* __restrict__ out, int mlp) {
  __shared__ float zt[KT][LSTRIDE];  // zt[k][j]
  __shared__ float wt[KT][LSTRIDE];  // wt[k][n]
  int bx = blockIdx.x;               // 4096 = 512 bi x 2 jh x 4 nb
  int nb = bx & 3;
  int jh = (bx >> 2) & 1;
  int bi = bx >> 3;                  // b*128 + i
  int b = bi >> 7;
  int j0 = jh * 64;
  int n0 = nb * 64;
  int tid = threadIdx.x;
  int tm = tid >> 4, tn = tid & 15;
  int lj = tid >> 2;                 // 0..63  z-load j row
  int lk4 = (tid & 3) * 4;           // z-load k chunk
  int lkk = tid >> 4;                // 0..15  W-load k row
  int ln4 = (tid & 15) * 4;          // W-load n chunk

  const float* urow = uv + (long)bi * 2048;
  const float* vrow = uv + (long)(b * 128 + j0 + lj) * 2048 + 1024;

  float acc[4][4] = {};

  for (int k0 = 0; k0 < 1024; k0 += KT) {
    floatx4 uu = *(const floatx4*)(urow + k0 + lk4);
    floatx4 vv = *(const floatx4*)(vrow + k0 + lk4);
    floatx4 wa = *(const floatx4*)(W2 + (long)(k0 + lkk) * 256 + n0 + ln4);
    __syncthreads();
#pragma unroll
    for (int e = 0; e < 4; e++) {
      float z = uu[e] + vv[e];
      zt[lk4 + e][lj] = z > 0.f ? z : 0.f;
    }
    *(floatx4*)&wt[lkk][ln4] = wa;
    __syncthreads();
#pragma unroll
    for (int kk = 0; kk < KT; kk++) {
      floatx4 zv = *(const floatx4*)&zt[kk][tm * 4];
      floatx4 wv = *(const floatx4*)&wt[kk][tn * 4];
#pragma unroll
      for (int mm = 0; mm < 4; mm++)
#pragma unroll
        for (int nn = 0; nn < 4; nn++)
          acc[mm][nn] += zv[mm] * wv[nn];
    }
  }
  float* ob = out + (long)(bi * 128 + j0) * 774 + mlp * 258 + n0 + tn * 4;
#pragma unroll
  for (int mm = 0; mm < 4; mm++) {
    float* orow = ob + (long)(tm * 4 + mm) * 774;
    floatx2 pa, pb;
    pa[0] = acc[mm][0] > 0.f ? acc[mm][0] : 0.f;
    pa[1] = acc[mm][1] > 0.f ? acc[mm][1] : 0.f;
    pb[0] = acc[mm][2] > 0.f ? acc[mm][2] : 0.f;
    pb[1] = acc[mm][3] > 0.f ? acc[mm][3] : 0.f;
    *(floatx2*)orow = pa;
    *(floatx2*)(orow + 2) = pb;
  }
}

// ---------------------------------------------------------------------------
// Kernel 3: heads (unchanged). One wave per (g,row).
// ---------------------------------------------------------------------------
__global__ __launch_bounds__(256) void head_kernel(
    const float* __restrict__ w3_0, const float* __restrict__ w3_1,
    const float* __restrict__ w3_2, float* out) {
  int wid = threadIdx.x >> 6, lane = threadIdx.x & 63;
  int r = blockIdx.x * 4 + wid;   // [0, 196608)
  int mlp = r >> 16;
  int row = r & 65535;            // (b*128+i)*128 + j
  const float* w3 = (mlp == 0) ? w3_0 : (mlp == 1) ? w3_1 : w3_2;
  const float* yp = out + (long)row * 774 + mlp * 258 + lane * 4;
  floatx2 ya = *(const floatx2*)yp;
  floatx2 yb = *(const floatx2*)(yp + 2);
  const float* wp = w3 + lane * 8;
  floatx4 wv0 = *(const floatx4*)wp;
  floatx4 wv1 = *(const floatx4*)(wp + 4);
  float s0 = ya[0] * wv0[0] + ya[1] * wv0[2] + yb[0] * wv1[0] + yb[1] * wv1[2];
  float s1 = ya[0] * wv0[1] + ya[1] * wv0[3] + yb[0] * wv1[1] + yb[1] * wv1[3];
#pragma unroll
  for (int off = 32; off > 0; off >>= 1) {
    s0 += __shfl_xor(s0, off, 64);
    s1 += __shfl_xor(s1, off, 64);
  }
  if (lane == 0) {
    float m = fmaxf(s0, s1);
    float e0 = __expf(s0 - m), e1 = __expf(s1 - m);
    float inv = 1.0f / (e0 + e1);
    floatx2 pr;
    pr[0] = e0 * inv;
    pr[1] = e1 * inv;
    *(floatx2*)(out + (long)row * 774 + mlp * 258 + 256) = pr;
  }
}

extern "C" void kernel_launch(void* const* d_in, const int* in_sizes, int n_in,
                              void* d_out, int out_size, void* d_ws, size_t ws_size,
                              hipStream_t stream) {
  const float* para = (const float*)d_in[0];
  const float* Wf1  = (const float*)d_in[1];
  const float* Wf2  = (const float*)d_in[2];
  const float* w3   = (const float*)d_in[3];
  const float* Wh1a = (const float*)d_in[4];
  const float* Wh1b = (const float*)d_in[5];
  const float* wl1  = (const float*)d_in[6];
  const float* Wh2a = (const float*)d_in[7];
  const float* Wh2b = (const float*)d_in[8];
  const float* wl2  = (const float*)d_in[9];

  float* uv = (float*)d_ws;                        // 4 MiB
  unsigned short* w2f =
      (unsigned short*)((char*)d_ws + (4u << 20)); // 1 MiB (MFMA path)
  float* outp = (float*)d_out;                     // f32 [4*128*128][774]

  bool mfma_ok = ws_size >= (size_t)(5u << 20);

  const float* W1s[3] = {Wf1, Wh1a, Wh2a};
  const float* W2s[3] = {Wf2, Wh1b, Wh2b};
  for (int mlp = 0; mlp < 3; mlp++) {
    stage1_valu<<<256, 256, 0, stream>>>(para, W1s[mlp], uv);
    if (mfma_ok) {
      prep_w2<<<128, 256, 0, stream>>>(W2s[mlp], w2f);
      pair_mfma<<<512, 256, 0, stream>>>(uv, w2f, outp, mlp);
    } else {
      pair_valu<<<4096, 256, 0, stream>>>(uv, W2s[mlp], outp, mlp);
    }
  }
  head_kernel<<<49152, 256, 0, stream>>>(w3, wl1, wl2, outp);
}

// Round 2
// 580.198 us; speedup vs baseline: 2.7237x; 2.0857x over previous
//
#include <hip/hip_runtime.h>

// PointerNet: B=4, N=128, H=512, d_pair=256.
// Interface (verified):
//   inputs  f32, setup_inputs dict order
//   d_out   f32, 50,724,864 elements = [4][128][128][774]
// Per mlp g in {future(Wf1,Wf2,w3), hist1(Wh1a,Wh1b,wl1), hist2(Wh2a,Wh2b,wl2)}:
//   uv[m][c'] = sum_h P[m][h] * W1[(c'>=1024?512:0)+h][c'&1023]     (m = b*128+i)
//   y[bi,j,n] = relu( sum_k relu(uv[bi][k] + uv[bj][1024+k]) * W2[k][n] )
//   p = softmax_c( sum_n y[n] * w3[n][c] )
//   out[((bi)*128+j)*774 + g*258 + {n | 256+c}] = {y | p}
// Workspace: uv f32 [512][2048] = 4 MiB at ws+0 (reused per mlp);
//            W2F bf16 frag layout = 1 MiB at ws+4MiB (MFMA path only).
//
// R10 change (this round): pair_mfma was latency-bound (MfmaUtil 13.6%,
// VALUBusy 8%, occ 22.6%) on per-wave L2 re-reads of W2F (32x16B loads/K-tile
// vs 96 MFMA). Now: W2F K-slice (32 KB) staged per-BLOCK into LDS via async
// global_load_lds, double-buffered (T3 2-phase); B-frags via ds_read_b128.
// Head (y@w3 + softmax) fused into the pair epilogue (wave owns full n-range)
// -> head_kernel launch (200 MB HBM re-read) eliminated on the MFMA path.

typedef __attribute__((ext_vector_type(4))) float floatx4;
typedef __attribute__((ext_vector_type(2))) float floatx2;
typedef __attribute__((ext_vector_type(8))) short short8;

#define KT 16
#define LSTRIDE 68  // 64 + 4 pad (LDS bank-conflict break)

__device__ __forceinline__ void gload_lds16(const void* g, void* l) {
  __builtin_amdgcn_global_load_lds(
      (const __attribute__((address_space(1))) void*)g,
      (__attribute__((address_space(3))) void*)l, 16, 0, 0);
}

// ---------------------------------------------------------------------------
// Kernel 1: stage1 f32 GEMM (unchanged, proven). Block = 64m x 64c tile.
// ---------------------------------------------------------------------------
__global__ __launch_bounds__(256) void stage1_valu(
    const float* __restrict__ P,    // [512][512]
    const float* __restrict__ W1,   // [1024][1024], one mlp
    float* __restrict__ uv) {       // [512][2048]
  __shared__ float at[KT][LSTRIDE];  // at[k][m]
  __shared__ float wt[KT][LSTRIDE];  // wt[k][c]
  int bx = blockIdx.x;
  int m0 = (bx >> 5) * 64;
  int c0 = (bx & 31) * 64;
  int half = c0 >> 10;            // 0: u-half (W1 rows 0..511), 1: v-half
  int ccol = c0 & 1023;
  int tid = threadIdx.x;
  int tm = tid >> 4, tn = tid & 15;
  int lm = tid >> 2;              // 0..63  A-load row
  int lk4 = (tid & 3) * 4;        // A-load k chunk
  int lkk = tid >> 4;             // 0..15  W-load k row
  int lc4 = (tid & 15) * 4;       // W-load c chunk

  float acc[4][4] = {};

  for (int k0 = 0; k0 < 512; k0 += KT) {
    floatx4 pa = *(const floatx4*)(P + (long)(m0 + lm) * 512 + k0 + lk4);
    floatx4 wa = *(const floatx4*)(W1 + (long)(half * 512 + k0 + lkk) * 1024 + ccol + lc4);
    __syncthreads();              // prev-iter LDS reads done
#pragma unroll
    for (int e = 0; e < 4; e++) at[lk4 + e][lm] = pa[e];
    *(floatx4*)&wt[lkk][lc4] = wa;
    __syncthreads();
#pragma unroll
    for (int kk = 0; kk < KT; kk++) {
      floatx4 av = *(const floatx4*)&at[kk][tm * 4];
      floatx4 wv = *(const floatx4*)&wt[kk][tn * 4];
#pragma unroll
      for (int mm = 0; mm < 4; mm++)
#pragma unroll
        for (int nn = 0; nn < 4; nn++)
          acc[mm][nn] += av[mm] * wv[nn];
    }
  }
#pragma unroll
  for (int mm = 0; mm < 4; mm++) {
    floatx4 o;
#pragma unroll
    for (int nn = 0; nn < 4; nn++) o[nn] = acc[mm][nn];
    *(floatx4*)(uv + (long)(m0 + tm * 4 + mm) * 2048 + c0 + tn * 4) = o;
  }
}

// ---------------------------------------------------------------------------
// Kernel 1b: W2 -> MFMA B-fragment layout, split-bf16 (truncated hi, lo).
// W2F[kt(32)][nf(16)][hl(2)][lane(64)][e(8)] bf16-as-u16; 1 MiB.
// lane = 16g + c holds W2[kt*32 + g*8 + e][nf*16 + c]  (same slot->k map as A).
// ---------------------------------------------------------------------------
__global__ __launch_bounds__(256) void prep_w2(
    const float* __restrict__ W2,          // [1024][256]
    unsigned short* __restrict__ W2F) {
  int t = blockIdx.x * 256 + threadIdx.x;  // 32768 threads total
  int lane = t & 63;
  int nf = (t >> 6) & 15;
  int kt = t >> 10;                        // 0..31
  int g = lane >> 4, c = lane & 15;
  int n = nf * 16 + c;
  int kbase = kt * 32 + g * 8;

  union U { unsigned u[4]; short8 s; };
  U H, L;
  unsigned hb[8], lb[8];
#pragma unroll
  for (int e = 0; e < 8; e++) {
    float w = W2[(long)(kbase + e) * 256 + n];
    unsigned wb = __float_as_uint(w);
    unsigned h = wb & 0xFFFF0000u;
    float l = w - __uint_as_float(h);       // exact
    hb[e] = h;
    lb[e] = __float_as_uint(l) & 0xFFFF0000u;
  }
#pragma unroll
  for (int p = 0; p < 4; p++) {
    H.u[p] = __builtin_amdgcn_perm(hb[2 * p + 1], hb[2 * p], 0x07060302u);
    L.u[p] = __builtin_amdgcn_perm(lb[2 * p + 1], lb[2 * p], 0x07060302u);
  }
  long base = (((long)kt * 16 + nf) * 2) * 64 + lane;
  *(short8*)(W2F + (base + 0) * 8) = H.s;
  *(short8*)(W2F + (base + 64) * 8) = L.s;   // hl=1 slot
}

// ---------------------------------------------------------------------------
// Kernel 2 (hot): pair GEMM via split-bf16 MFMA, LDS-staged B, fused head.
// One block per bi; 4 waves, wave w owns j rows [w*32, w*32+32), all 256 n.
// acc = zhi@whi + zlo@whi + zhi@wlo accumulated in f32 AGPRs.
// B K-slices (32 KB) double-buffered in LDS via async global_load_lds.
// ---------------------------------------------------------------------------
__device__ __forceinline__ void make_frag(
    const floatx4& ua, const floatx4& ub,
    const floatx4& va, const floatx4& vb,
    short8& hi, short8& lo) {
  unsigned hb[8], lb[8];
#pragma unroll
  for (int e = 0; e < 8; e++) {
    float z = (e < 4) ? (ua[e] + va[e]) : (ub[e - 4] + vb[e - 4]);
    z = fmaxf(z, 0.0f);
    unsigned zb = __float_as_uint(z);
    unsigned h = zb & 0xFFFF0000u;
    float l = z - __uint_as_float(h);       // exact remainder
    hb[e] = h;
    lb[e] = __float_as_uint(l) & 0xFFFF0000u;
  }
  union U { unsigned u[4]; short8 s; };
  U H, L;
#pragma unroll
  for (int p = 0; p < 4; p++) {
    H.u[p] = __builtin_amdgcn_perm(hb[2 * p + 1], hb[2 * p], 0x07060302u);
    L.u[p] = __builtin_amdgcn_perm(lb[2 * p + 1], lb[2 * p], 0x07060302u);
  }
  hi = H.s;
  lo = L.s;
}

__global__ __launch_bounds__(256, 2) void pair_mfma(
    const float* __restrict__ uv,           // [512][2048]
    const unsigned short* __restrict__ W2F, // frag layout, 1 MiB
    const float* __restrict__ w3,           // [256][2] head weights, this mlp
    float* __restrict__ out, int mlp) {
  __shared__ unsigned short wbuf[2][16384]; // 2 x 32 KB double buffer
  int bi = blockIdx.x;          // 0..511 = b*128 + i
  int b = bi >> 7;
  int tid = threadIdx.x;
  int wid = tid >> 6;           // wave 0..3 -> j rows [wid*32, wid*32+32)
  int lane = tid & 63;
  int g = lane >> 4;            // k-chunk selector
  int r = lane & 15;            // A row within 16-tile / D col within 16-tile
  int wj = wid * 32;

  const float* ubase = uv + (long)bi * 2048;                          // u[k]
  const float* v0 = uv + (long)(b * 128 + wj + r) * 2048 + 1024;      // rows wj+r
  const float* v1 = v0 + 16 * 2048;                                   // rows wj+16+r

  floatx4 acc[2][16];
#pragma unroll
  for (int mm = 0; mm < 2; mm++)
#pragma unroll
    for (int nf = 0; nf < 16; nf++) acc[mm][nf] = (floatx4){0.f, 0.f, 0.f, 0.f};

  // Prologue: stage kt=0 slice into buf0 (8 x 16B chunks per thread).
  {
    const unsigned short* gs = W2F;   // kt = 0 slice, 16384 shorts
#pragma unroll
    for (int i = 0; i < 8; i++)
      gload_lds16(gs + (i * 256 + wid * 64 + lane) * 8,
                  &wbuf[0][(i * 256 + wid * 64) * 8]);
  }
  __syncthreads();   // drains vmcnt(0): slice 0 resident

  int cur = 0;
  for (int kt = 0; kt < 32; kt++) {
    // Issue next-slice prefetch FIRST (flies under this tile's compute).
    if (kt < 31) {
      const unsigned short* gs = W2F + (long)(kt + 1) * 16384;
#pragma unroll
      for (int i = 0; i < 8; i++)
        gload_lds16(gs + (i * 256 + wid * 64 + lane) * 8,
                    &wbuf[cur ^ 1][(i * 256 + wid * 64) * 8]);
    }

    int k0 = kt * 32 + g * 8;
    floatx4 u0  = *(const floatx4*)(ubase + k0);
    floatx4 u1  = *(const floatx4*)(ubase + k0 + 4);
    floatx4 va0 = *(const floatx4*)(v0 + k0);
    floatx4 va1 = *(const floatx4*)(v0 + k0 + 4);
    floatx4 vb0 = *(const floatx4*)(v1 + k0);
    floatx4 vb1 = *(const floatx4*)(v1 + k0 + 4);

    short8 ahi[2], alo[2];
    make_frag(u0, u1, va0, va1, ahi[0], alo[0]);
    make_frag(u0, u1, vb0, vb1, ahi[1], alo[1]);

    const unsigned short* wf = &wbuf[cur][lane * 8];
#pragma unroll
    for (int nf = 0; nf < 16; nf++) {
      short8 whi = *(const short8*)(wf + (nf * 2 + 0) * 512);
      short8 wlo = *(const short8*)(wf + (nf * 2 + 1) * 512);
#pragma unroll
      for (int mm = 0; mm < 2; mm++) {
        acc[mm][nf] = __builtin_amdgcn_mfma_f32_16x16x32_bf16(
            ahi[mm], whi, acc[mm][nf], 0, 0, 0);
        acc[mm][nf] = __builtin_amdgcn_mfma_f32_16x16x32_bf16(
            alo[mm], whi, acc[mm][nf], 0, 0, 0);
        acc[mm][nf] = __builtin_amdgcn_mfma_f32_16x16x32_bf16(
            ahi[mm], wlo, acc[mm][nf], 0, 0, 0);
      }
    }
    __syncthreads();   // next slice resident + this buffer's reads drained
    cur ^= 1;
  }

  // Epilogue: D layout col = lane&15 (n), row = (lane>>4)*4 + reg (j).
  // Fused head: s_c = sum_n y*w3[n][c]; 16 lanes (r=0..15, fixed g) share a
  // row and together cover all 256 n -> xor-reduce over offsets 1,2,4,8.
  float* ob = out + (long)(bi * 128) * 774 + mlp * 258;
  floatx2 w3v[16];
#pragma unroll
  for (int nf = 0; nf < 16; nf++)
    w3v[nf] = *(const floatx2*)(w3 + (nf * 16 + r) * 2);
#pragma unroll
  for (int mm = 0; mm < 2; mm++) {
    int jrow = wj + mm * 16 + g * 4;
#pragma unroll
    for (int reg = 0; reg < 4; reg++) {
      float* orow = ob + (long)(jrow + reg) * 774;
      float s0 = 0.f, s1 = 0.f;
#pragma unroll
      for (int nf = 0; nf < 16; nf++) {
        float y = acc[mm][nf][reg];
        y = y > 0.f ? y : 0.f;
        orow[nf * 16 + r] = y;
        s0 += y * w3v[nf][0];
        s1 += y * w3v[nf][1];
      }
#pragma unroll
      for (int off = 1; off < 16; off <<= 1) {
        s0 += __shfl_xor(s0, off, 64);
        s1 += __shfl_xor(s1, off, 64);
      }
      if (r == 0) {
        float m = fmaxf(s0, s1);
        float e0 = __expf(s0 - m), e1 = __expf(s1 - m);
        float inv = 1.0f / (e0 + e1);
        floatx2 pr;
        pr[0] = e0 * inv;
        pr[1] = e1 * inv;
        *(floatx2*)(orow + 256) = pr;   // even elem offset -> 8B aligned
      }
    }
  }
}

// ---------------------------------------------------------------------------
// Kernel 2-fallback: original f32 VALU pair GEMM (used only if ws too small).
// ---------------------------------------------------------------------------
__global__ __launch_bounds__(256) void pair_valu(
    const float* __restrict__ uv,   // [512][2048], this mlp
    const float* __restrict__ W2,   // [1024][256], this mlp
    float* __restrict__ out, int mlp) {
  __shared__ float zt[KT][LSTRIDE];  // zt[k][j]
  __shared__ float wt[KT][LSTRIDE];  // wt[k][n]
  int bx = blockIdx.x;               // 4096 = 512 bi x 2 jh x 4 nb
  int nb = bx & 3;
  int jh = (bx >> 2) & 1;
  int bi = bx >> 3;                  // b*128 + i
  int b = bi >> 7;
  int j0 = jh * 64;
  int n0 = nb * 64;
  int tid = threadIdx.x;
  int tm = tid >> 4, tn = tid & 15;
  int lj = tid >> 2;                 // 0..63  z-load j row
  int lk4 = (tid & 3) * 4;           // z-load k chunk
  int lkk = tid >> 4;                // 0..15  W-load k row
  int ln4 = (tid & 15) * 4;          // W-load n chunk

  const float* urow = uv + (long)bi * 2048;
  const float* vrow = uv + (long)(b * 128 + j0 + lj) * 2048 + 1024;

  float acc[4][4] = {};

  for (int k0 = 0; k0 < 1024; k0 += KT) {
    floatx4 uu = *(const floatx4*)(urow + k0 + lk4);
    floatx4 vv = *(const floatx4*)(vrow + k0 + lk4);
    floatx4 wa = *(const floatx4*)(W2 + (long)(k0 + lkk) * 256 + n0 + ln4);
    __syncthreads();
#pragma unroll
    for (int e = 0; e < 4; e++) {
      float z = uu[e] + vv[e];
      zt[lk4 + e][lj] = z > 0.f ? z : 0.f;
    }
    *(floatx4*)&wt[lkk][ln4] = wa;
    __syncthreads();
#pragma unroll
    for (int kk = 0; kk < KT; kk++) {
      floatx4 zv = *(const floatx4*)&zt[kk][tm * 4];
      floatx4 wv = *(const floatx4*)&wt[kk][tn * 4];
#pragma unroll
      for (int mm = 0; mm < 4; mm++)
#pragma unroll
        for (int nn = 0; nn < 4; nn++)
          acc[mm][nn] += zv[mm] * wv[nn];
    }
  }
  float* ob = out + (long)(bi * 128 + j0) * 774 + mlp * 258 + n0 + tn * 4;
#pragma unroll
  for (int mm = 0; mm < 4; mm++) {
    float* orow = ob + (long)(tm * 4 + mm) * 774;
    floatx2 pa, pb;
    pa[0] = acc[mm][0] > 0.f ? acc[mm][0] : 0.f;
    pa[1] = acc[mm][1] > 0.f ? acc[mm][1] : 0.f;
    pb[0] = acc[mm][2] > 0.f ? acc[mm][2] : 0.f;
    pb[1] = acc[mm][3] > 0.f ? acc[mm][3] : 0.f;
    *(floatx2*)orow = pa;
    *(floatx2*)(orow + 2) = pb;
  }
}

// ---------------------------------------------------------------------------
// Kernel 3: heads (fallback path only). One wave per (g,row).
// ---------------------------------------------------------------------------
__global__ __launch_bounds__(256) void head_kernel(
    const float* __restrict__ w3_0, const float* __restrict__ w3_1,
    const float* __restrict__ w3_2, float* out) {
  int wid = threadIdx.x >> 6, lane = threadIdx.x & 63;
  int r = blockIdx.x * 4 + wid;   // [0, 196608)
  int mlp = r >> 16;
  int row = r & 65535;            // (b*128+i)*128 + j
  const float* w3 = (mlp == 0) ? w3_0 : (mlp == 1) ? w3_1 : w3_2;
  const float* yp = out + (long)row * 774 + mlp * 258 + lane * 4;
  floatx2 ya = *(const floatx2*)yp;
  floatx2 yb = *(const floatx2*)(yp + 2);
  const float* wp = w3 + lane * 8;
  floatx4 wv0 = *(const floatx4*)wp;
  floatx4 wv1 = *(const floatx4*)(wp + 4);
  float s0 = ya[0] * wv0[0] + ya[1] * wv0[2] + yb[0] * wv1[0] + yb[1] * wv1[2];
  float s1 = ya[0] * wv0[1] + ya[1] * wv0[3] + yb[0] * wv1[1] + yb[1] * wv1[3];
#pragma unroll
  for (int off = 32; off > 0; off >>= 1) {
    s0 += __shfl_xor(s0, off, 64);
    s1 += __shfl_xor(s1, off, 64);
  }
  if (lane == 0) {
    float m = fmaxf(s0, s1);
    float e0 = __expf(s0 - m), e1 = __expf(s1 - m);
    float inv = 1.0f / (e0 + e1);
    floatx2 pr;
    pr[0] = e0 * inv;
    pr[1] = e1 * inv;
    *(floatx2*)(out + (long)row * 774 + mlp * 258 + 256) = pr;
  }
}

extern "C" void kernel_launch(void* const* d_in, const int* in_sizes, int n_in,
                              void* d_out, int out_size, void* d_ws, size_t ws_size,
                              hipStream_t stream) {
  const float* para = (const float*)d_in[0];
  const float* Wf1  = (const float*)d_in[1];
  const float* Wf2  = (const float*)d_in[2];
  const float* w3   = (const float*)d_in[3];
  const float* Wh1a = (const float*)d_in[4];
  const float* Wh1b = (const float*)d_in[5];
  const float* wl1  = (const float*)d_in[6];
  const float* Wh2a = (const float*)d_in[7];
  const float* Wh2b = (const float*)d_in[8];
  const float* wl2  = (const float*)d_in[9];

  float* uv = (float*)d_ws;                        // 4 MiB
  unsigned short* w2f =
      (unsigned short*)((char*)d_ws + (4u << 20)); // 1 MiB (MFMA path)
  float* outp = (float*)d_out;                     // f32 [4*128*128][774]

  bool mfma_ok = ws_size >= (size_t)(5u << 20);

  const float* W1s[3] = {Wf1, Wh1a, Wh2a};
  const float* W2s[3] = {Wf2, Wh1b, Wh2b};
  const float* w3s[3] = {w3, wl1, wl2};
  for (int mlp = 0; mlp < 3; mlp++) {
    stage1_valu<<<256, 256, 0, stream>>>(para, W1s[mlp], uv);
    if (mfma_ok) {
      prep_w2<<<128, 256, 0, stream>>>(W2s[mlp], w2f);
      pair_mfma<<<512, 256, 0, stream>>>(uv, w2f, w3s[mlp], outp, mlp);
    } else {
      pair_valu<<<4096, 256, 0, stream>>>(uv, W2s[mlp], outp, mlp);
    }
  }
  if (!mfma_ok) head_kernel<<<49152, 256, 0, stream>>>(w3, wl1, wl2, outp);
}

// Round 3
// 545.184 us; speedup vs baseline: 2.8987x; 1.0642x over previous
//
#include <hip/hip_runtime.h>

// PointerNet: B=4, N=128, H=512, d_pair=256.
// Interface (verified):
//   inputs  f32, setup_inputs dict order
//   d_out   f32, 50,724,864 elements = [4][128][128][774]
// Per mlp g in {future(Wf1,Wf2,w3), hist1(Wh1a,Wh1b,wl1), hist2(Wh2a,Wh2b,wl2)}:
//   uv[m][c'] = sum_h P[m][h] * W1[(c'>=1024?512:0)+h][c'&1023]     (m = b*128+i)
//   y[bi,j,n] = relu( sum_k relu(uv[bi][k] + uv[bj][1024+k]) * W2[k][n] )
//   p = softmax_c( sum_n y[n] * w3[n][c] )
//   out[((bi)*128+j)*774 + g*258 + {n | 256+c}] = {y | p}
// Workspace layout:
//   uv  f32 [512][2048]          4 MiB @ ws+0        (reused per mlp)
//   W2F bf16 frag layout         1 MiB @ ws+4MiB     (pair MFMA path, ws>=5MiB)
//   W1F bf16 frag layout         4 MiB @ ws+5MiB     (stage1 MFMA path, ws>=9MiB)
//
// R11 changes: (a) pair_mfma occupancy was register-capped at 2 waves/SIMD
// (92 VGPR + 128 AGPR acc) -> restructure to 8-wave blocks, wave = 32j x 128n
// (acc 64), launch_bounds(512,4) => 4 waves/SIMD; head partials combined via
// LDS scratch. (b) stage1 moved to split-bf16 MFMA (prep_w1f bakes the u/v
// row split into fragment layout), guarded on ws>=9MiB.

typedef __attribute__((ext_vector_type(4))) float floatx4;
typedef __attribute__((ext_vector_type(2))) float floatx2;
typedef __attribute__((ext_vector_type(8))) short short8;

#define KT 16
#define LSTRIDE 68  // 64 + 4 pad (LDS bank-conflict break)

__device__ __forceinline__ void gload_lds16(const void* g, void* l) {
  __builtin_amdgcn_global_load_lds(
      (const __attribute__((address_space(1))) void*)g,
      (__attribute__((address_space(3))) void*)l, 16, 0, 0);
}

// Split 8 f32 into bf16 hi (truncated) + bf16 lo (exact remainder, truncated).
__device__ __forceinline__ void split8(const float* x, short8& hi, short8& lo) {
  unsigned hb[8], lb[8];
#pragma unroll
  for (int e = 0; e < 8; e++) {
    unsigned xb = __float_as_uint(x[e]);
    unsigned h = xb & 0xFFFF0000u;
    float l = x[e] - __uint_as_float(h);    // exact
    hb[e] = h;
    lb[e] = __float_as_uint(l) & 0xFFFF0000u;
  }
  union U { unsigned u[4]; short8 s; };
  U H, L;
#pragma unroll
  for (int p = 0; p < 4; p++) {
    H.u[p] = __builtin_amdgcn_perm(hb[2 * p + 1], hb[2 * p], 0x07060302u);
    L.u[p] = __builtin_amdgcn_perm(lb[2 * p + 1], lb[2 * p], 0x07060302u);
  }
  hi = H.s;
  lo = L.s;
}

// ---------------------------------------------------------------------------
// Kernel 0a: W1 -> MFMA B-fragment layout with the u/v row split baked in.
// W1X[k][c'] = W1[(c'>=1024?512:0)+k][c'&1023], k in [0,512), c' in [0,2048).
// W1F[kt(16)][NF(128)][hl(2)][lane(64)][e(8)] bf16-as-u16; 4 MiB.
// lane = 16g + c holds W1X[kt*32 + g*8 + e][NF*16 + c].
// ---------------------------------------------------------------------------
__global__ __launch_bounds__(256) void prep_w1f(
    const float* __restrict__ W1,          // [1024][1024]
    unsigned short* __restrict__ W1F) {
  int t = blockIdx.x * 256 + threadIdx.x;  // 131072 threads
  int lane = t & 63;
  int nf = (t >> 6) & 127;
  int kt = t >> 13;                        // 0..15
  int g = lane >> 4, c = lane & 15;
  int n = nf * 16 + c;                     // 0..2047
  int kbase = kt * 32 + g * 8;
  const float* src = W1 + (long)((n >= 1024 ? 512 : 0) + kbase) * 1024 + (n & 1023);

  unsigned hb[8], lb[8];
#pragma unroll
  for (int e = 0; e < 8; e++) {
    float w = src[(long)e * 1024];
    unsigned wb = __float_as_uint(w);
    unsigned h = wb & 0xFFFF0000u;
    float l = w - __uint_as_float(h);
    hb[e] = h;
    lb[e] = __float_as_uint(l) & 0xFFFF0000u;
  }
  union U { unsigned u[4]; short8 s; };
  U H, L;
#pragma unroll
  for (int p = 0; p < 4; p++) {
    H.u[p] = __builtin_amdgcn_perm(hb[2 * p + 1], hb[2 * p], 0x07060302u);
    L.u[p] = __builtin_amdgcn_perm(lb[2 * p + 1], lb[2 * p], 0x07060302u);
  }
  long base = ((long)kt * 128 + nf) * 2 * 64 + lane;
  *(short8*)(W1F + (base + 0) * 8) = H.s;
  *(short8*)(W1F + (base + 64) * 8) = L.s;
}

// ---------------------------------------------------------------------------
// Kernel 1: stage1 via split-bf16 MFMA. uv[m][c'] = P[m] @ W1X[:, c'].
// Grid 512 = 32 mblk(16 rows) x 16 nblk(128 cols); 4 waves, wave = 16m x 32n.
// B frags direct from W1F (L2-resident). acc 8 regs -> high occupancy.
// ---------------------------------------------------------------------------
__global__ __launch_bounds__(256) void stage1_mfma(
    const float* __restrict__ P,           // [512][512]
    const unsigned short* __restrict__ W1F,
    float* __restrict__ uv) {              // [512][2048]
  int bx = blockIdx.x;
  int m0 = (bx >> 4) * 16;
  int n0 = (bx & 15) * 128;
  int tid = threadIdx.x;
  int wid = tid >> 6, lane = tid & 63;
  int g = lane >> 4, r = lane & 15;
  int nw0 = n0 + wid * 32;                 // wave covers 2 n-frags

  const float* prow = P + (long)(m0 + r) * 512;

  floatx4 acc[2];
#pragma unroll
  for (int nf = 0; nf < 2; nf++) acc[nf] = (floatx4){0.f, 0.f, 0.f, 0.f};

  for (int kt = 0; kt < 16; kt++) {
    int k0 = kt * 32 + g * 8;
    float a[8];
    floatx4 a0 = *(const floatx4*)(prow + k0);
    floatx4 a1 = *(const floatx4*)(prow + k0 + 4);
#pragma unroll
    for (int e = 0; e < 4; e++) { a[e] = a0[e]; a[4 + e] = a1[e]; }
    short8 ahi, alo;
    split8(a, ahi, alo);
#pragma unroll
    for (int nf = 0; nf < 2; nf++) {
      int nfg = (nw0 >> 4) + nf;
      const unsigned short* wp = W1F + (((long)kt * 128 + nfg) * 2 * 64 + lane) * 8;
      short8 whi = *(const short8*)wp;
      short8 wlo = *(const short8*)(wp + 64 * 8);
      acc[nf] = __builtin_amdgcn_mfma_f32_16x16x32_bf16(ahi, whi, acc[nf], 0, 0, 0);
      acc[nf] = __builtin_amdgcn_mfma_f32_16x16x32_bf16(alo, whi, acc[nf], 0, 0, 0);
      acc[nf] = __builtin_amdgcn_mfma_f32_16x16x32_bf16(ahi, wlo, acc[nf], 0, 0, 0);
    }
  }
  // D: row = g*4 + reg (m), col = r (n)
#pragma unroll
  for (int nf = 0; nf < 2; nf++)
#pragma unroll
    for (int reg = 0; reg < 4; reg++)
      uv[(long)(m0 + g * 4 + reg) * 2048 + nw0 + nf * 16 + r] = acc[nf][reg];
}

// ---------------------------------------------------------------------------
// Kernel 1-fallback: stage1 f32 VALU GEMM (proven; used if ws < 9 MiB).
// ---------------------------------------------------------------------------
__global__ __launch_bounds__(256) void stage1_valu(
    const float* __restrict__ P,    // [512][512]
    const float* __restrict__ W1,   // [1024][1024], one mlp
    float* __restrict__ uv) {       // [512][2048]
  __shared__ float at[KT][LSTRIDE];
  __shared__ float wt[KT][LSTRIDE];
  int bx = blockIdx.x;
  int m0 = (bx >> 5) * 64;
  int c0 = (bx & 31) * 64;
  int half = c0 >> 10;
  int ccol = c0 & 1023;
  int tid = threadIdx.x;
  int tm = tid >> 4, tn = tid & 15;
  int lm = tid >> 2;
  int lk4 = (tid & 3) * 4;
  int lkk = tid >> 4;
  int lc4 = (tid & 15) * 4;

  float acc[4][4] = {};

  for (int k0 = 0; k0 < 512; k0 += KT) {
    floatx4 pa = *(const floatx4*)(P + (long)(m0 + lm) * 512 + k0 + lk4);
    floatx4 wa = *(const floatx4*)(W1 + (long)(half * 512 + k0 + lkk) * 1024 + ccol + lc4);
    __syncthreads();
#pragma unroll
    for (int e = 0; e < 4; e++) at[lk4 + e][lm] = pa[e];
    *(floatx4*)&wt[lkk][lc4] = wa;
    __syncthreads();
#pragma unroll
    for (int kk = 0; kk < KT; kk++) {
      floatx4 av = *(const floatx4*)&at[kk][tm * 4];
      floatx4 wv = *(const floatx4*)&wt[kk][tn * 4];
#pragma unroll
      for (int mm = 0; mm < 4; mm++)
#pragma unroll
        for (int nn = 0; nn < 4; nn++)
          acc[mm][nn] += av[mm] * wv[nn];
    }
  }
#pragma unroll
  for (int mm = 0; mm < 4; mm++) {
    floatx4 o;
#pragma unroll
    for (int nn = 0; nn < 4; nn++) o[nn] = acc[mm][nn];
    *(floatx4*)(uv + (long)(m0 + tm * 4 + mm) * 2048 + c0 + tn * 4) = o;
  }
}

// ---------------------------------------------------------------------------
// Kernel 1b: W2 -> MFMA B-fragment layout (unchanged, proven).
// W2F[kt(32)][nf(16)][hl(2)][lane(64)][e(8)] bf16-as-u16; 1 MiB.
// ---------------------------------------------------------------------------
__global__ __launch_bounds__(256) void prep_w2(
    const float* __restrict__ W2,          // [1024][256]
    unsigned short* __restrict__ W2F) {
  int t = blockIdx.x * 256 + threadIdx.x;  // 32768 threads total
  int lane = t & 63;
  int nf = (t >> 6) & 15;
  int kt = t >> 10;                        // 0..31
  int g = lane >> 4, c = lane & 15;
  int n = nf * 16 + c;
  int kbase = kt * 32 + g * 8;

  unsigned hb[8], lb[8];
#pragma unroll
  for (int e = 0; e < 8; e++) {
    float w = W2[(long)(kbase + e) * 256 + n];
    unsigned wb = __float_as_uint(w);
    unsigned h = wb & 0xFFFF0000u;
    float l = w - __uint_as_float(h);
    hb[e] = h;
    lb[e] = __float_as_uint(l) & 0xFFFF0000u;
  }
  union U { unsigned u[4]; short8 s; };
  U H, L;
#pragma unroll
  for (int p = 0; p < 4; p++) {
    H.u[p] = __builtin_amdgcn_perm(hb[2 * p + 1], hb[2 * p], 0x07060302u);
    L.u[p] = __builtin_amdgcn_perm(lb[2 * p + 1], lb[2 * p], 0x07060302u);
  }
  long base = (((long)kt * 16 + nf) * 2) * 64 + lane;
  *(short8*)(W2F + (base + 0) * 8) = H.s;
  *(short8*)(W2F + (base + 64) * 8) = L.s;
}

// ---------------------------------------------------------------------------
// Kernel 2 (hot): pair GEMM via split-bf16 MFMA, LDS-staged B, fused head.
// 512 threads = 8 waves; wave wid: jq = wid>>1 (j rows [jq*32, jq*32+32)),
// nh = wid&1 (n cols [nh*128, nh*128+128)). acc[2][8] = 64 regs;
// launch_bounds(512,4) -> regs<=128 -> 2 blocks/CU, 4 waves/SIMD.
// ---------------------------------------------------------------------------
__device__ __forceinline__ void make_frag(
    const floatx4& ua, const floatx4& ub,
    const floatx4& va, const floatx4& vb,
    short8& hi, short8& lo) {
  float z[8];
#pragma unroll
  for (int e = 0; e < 4; e++) {
    z[e] = fmaxf(ua[e] + va[e], 0.0f);
    z[4 + e] = fmaxf(ub[e] + vb[e], 0.0f);
  }
  split8(z, hi, lo);
}

__global__ __launch_bounds__(512, 4) void pair_mfma(
    const float* __restrict__ uv,           // [512][2048]
    const unsigned short* __restrict__ W2F, // frag layout, 1 MiB
    const float* __restrict__ w3,           // [256][2] head weights, this mlp
    float* __restrict__ out, int mlp) {
  __shared__ unsigned short wbuf[2][16384]; // 2 x 32 KB double buffer
  int bi = blockIdx.x;          // 0..511 = b*128 + i
  int b = bi >> 7;
  int tid = threadIdx.x;
  int wid = tid >> 6;           // 0..7
  int lane = tid & 63;
  int jq = wid >> 1;            // j-quarter
  int nh = wid & 1;             // n-half
  int g = lane >> 4;
  int r = lane & 15;
  int wj = jq * 32;

  const float* ubase = uv + (long)bi * 2048;
  const float* v0 = uv + (long)(b * 128 + wj + r) * 2048 + 1024;
  const float* v1 = v0 + 16 * 2048;

  floatx4 acc[2][8];
#pragma unroll
  for (int mm = 0; mm < 2; mm++)
#pragma unroll
    for (int nf = 0; nf < 8; nf++) acc[mm][nf] = (floatx4){0.f, 0.f, 0.f, 0.f};

  // Prologue: stage kt=0 slice (32 KB; 4 x 16B chunks per thread).
#pragma unroll
  for (int i = 0; i < 4; i++)
    gload_lds16(W2F + (i * 512 + tid) * 8, &wbuf[0][(i * 512 + tid) * 8]);
  __syncthreads();   // drains vmcnt(0): slice 0 resident

  int cur = 0;
  for (int kt = 0; kt < 32; kt++) {
    // Issue next-slice prefetch FIRST (flies under this tile's compute).
    if (kt < 31) {
      const unsigned short* gs = W2F + (long)(kt + 1) * 16384;
#pragma unroll
      for (int i = 0; i < 4; i++)
        gload_lds16(gs + (i * 512 + tid) * 8, &wbuf[cur ^ 1][(i * 512 + tid) * 8]);
    }

    int k0 = kt * 32 + g * 8;
    floatx4 u0  = *(const floatx4*)(ubase + k0);
    floatx4 u1  = *(const floatx4*)(ubase + k0 + 4);
    floatx4 va0 = *(const floatx4*)(v0 + k0);
    floatx4 va1 = *(const floatx4*)(v0 + k0 + 4);
    floatx4 vb0 = *(const floatx4*)(v1 + k0);
    floatx4 vb1 = *(const floatx4*)(v1 + k0 + 4);

    short8 ahi[2], alo[2];
    make_frag(u0, u1, va0, va1, ahi[0], alo[0]);
    make_frag(u0, u1, vb0, vb1, ahi[1], alo[1]);

#pragma unroll
    for (int nf = 0; nf < 8; nf++) {
      int nfg = nh * 8 + nf;
      const unsigned short* wp = &wbuf[cur][(nfg * 2) * 512 + lane * 8];
      short8 whi = *(const short8*)wp;
      short8 wlo = *(const short8*)(wp + 512);
#pragma unroll
      for (int mm = 0; mm < 2; mm++) {
        acc[mm][nf] = __builtin_amdgcn_mfma_f32_16x16x32_bf16(
            ahi[mm], whi, acc[mm][nf], 0, 0, 0);
        acc[mm][nf] = __builtin_amdgcn_mfma_f32_16x16x32_bf16(
            alo[mm], whi, acc[mm][nf], 0, 0, 0);
        acc[mm][nf] = __builtin_amdgcn_mfma_f32_16x16x32_bf16(
            ahi[mm], wlo, acc[mm][nf], 0, 0, 0);
      }
    }
    __syncthreads();   // next slice resident + this buffer's reads drained
    cur ^= 1;
  }

  // Epilogue: D col = r (n within frag), row = g*4 + reg (j within m-frag).
  // y stores + per-n-half head partials; partials combined via LDS scratch.
  float* ps = (float*)wbuf;   // psum[row(128)][nh(2)][c(2)] floats = 2 KB
  float* ob = out + (long)(bi * 128) * 774 + mlp * 258;
  floatx2 w3v[8];
#pragma unroll
  for (int nf = 0; nf < 8; nf++)
    w3v[nf] = *(const floatx2*)(w3 + ((nh * 8 + nf) * 16 + r) * 2);
#pragma unroll
  for (int mm = 0; mm < 2; mm++) {
    int jrow = wj + mm * 16 + g * 4;
#pragma unroll
    for (int reg = 0; reg < 4; reg++) {
      float* orow = ob + (long)(jrow + reg) * 774 + nh * 128;
      float s0 = 0.f, s1 = 0.f;
#pragma unroll
      for (int nf = 0; nf < 8; nf++) {
        float y = acc[mm][nf][reg];
        y = y > 0.f ? y : 0.f;
        orow[nf * 16 + r] = y;
        s0 += y * w3v[nf][0];
        s1 += y * w3v[nf][1];
      }
#pragma unroll
      for (int off = 1; off < 16; off <<= 1) {
        s0 += __shfl_xor(s0, off, 64);
        s1 += __shfl_xor(s1, off, 64);
      }
      if (r == 0) {
        int row = jrow + reg;
        ps[(row * 2 + nh) * 2 + 0] = s0;
        ps[(row * 2 + nh) * 2 + 1] = s1;
      }
    }
  }
  __syncthreads();
  if (nh == 1 && lane < 32) {
    int row = wj + lane;
    float s0 = ps[(row * 2) * 2 + 0] + ps[(row * 2 + 1) * 2 + 0];
    float s1 = ps[(row * 2) * 2 + 1] + ps[(row * 2 + 1) * 2 + 1];
    float m = fmaxf(s0, s1);
    float e0 = __expf(s0 - m), e1 = __expf(s1 - m);
    float inv = 1.0f / (e0 + e1);
    floatx2 pr;
    pr[0] = e0 * inv;
    pr[1] = e1 * inv;
    *(floatx2*)(ob + (long)row * 774 + 256) = pr;   // 8B aligned
  }
}

// ---------------------------------------------------------------------------
// Kernel 2-fallback: original f32 VALU pair GEMM (used only if ws too small).
// ---------------------------------------------------------------------------
__global__ __launch_bounds__(256) void pair_valu(
    const float* __restrict__ uv,   // [512][2048], this mlp
    const float* __restrict__ W2,   // [1024][256], this mlp
    float* __restrict__ out, int mlp) {
  __shared__ float zt[KT][LSTRIDE];
  __shared__ float wt[KT][LSTRIDE];
  int bx = blockIdx.x;               // 4096 = 512 bi x 2 jh x 4 nb
  int nb = bx & 3;
  int jh = (bx >> 2) & 1;
  int bi = bx >> 3;
  int b = bi >> 7;
  int j0 = jh * 64;
  int n0 = nb * 64;
  int tid = threadIdx.x;
  int tm = tid >> 4, tn = tid & 15;
  int lj = tid >> 2;
  int lk4 = (tid & 3) * 4;
  int lkk = tid >> 4;
  int ln4 = (tid & 15) * 4;

  const float* urow = uv + (long)bi * 2048;
  const float* vrow = uv + (long)(b * 128 + j0 + lj) * 2048 + 1024;

  float acc[4][4] = {};

  for (int k0 = 0; k0 < 1024; k0 += KT) {
    floatx4 uu = *(const floatx4*)(urow + k0 + lk4);
    floatx4 vv = *(const floatx4*)(vrow + k0 + lk4);
    floatx4 wa = *(const floatx4*)(W2 + (long)(k0 + lkk) * 256 + n0 + ln4);
    __syncthreads();
#pragma unroll
    for (int e = 0; e < 4; e++) {
      float z = uu[e] + vv[e];
      zt[lk4 + e][lj] = z > 0.f ? z : 0.f;
    }
    *(floatx4*)&wt[lkk][ln4] = wa;
    __syncthreads();
#pragma unroll
    for (int kk = 0; kk < KT; kk++) {
      floatx4 zv = *(const floatx4*)&zt[kk][tm * 4];
      floatx4 wv = *(const floatx4*)&wt[kk][tn * 4];
#pragma unroll
      for (int mm = 0; mm < 4; mm++)
#pragma unroll
        for (int nn = 0; nn < 4; nn++)
          acc[mm][nn] += zv[mm] * wv[nn];
    }
  }
  float* ob = out + (long)(bi * 128 + j0) * 774 + mlp * 258 + n0 + tn * 4;
#pragma unroll
  for (int mm = 0; mm < 4; mm++) {
    float* orow = ob + (long)(tm * 4 + mm) * 774;
    floatx2 pa, pb;
    pa[0] = acc[mm][0] > 0.f ? acc[mm][0] : 0.f;
    pa[1] = acc[mm][1] > 0.f ? acc[mm][1] : 0.f;
    pb[0] = acc[mm][2] > 0.f ? acc[mm][2] : 0.f;
    pb[1] = acc[mm][3] > 0.f ? acc[mm][3] : 0.f;
    *(floatx2*)orow = pa;
    *(floatx2*)(orow + 2) = pb;
  }
}

// ---------------------------------------------------------------------------
// Kernel 3: heads (fallback path only). One wave per (g,row).
// ---------------------------------------------------------------------------
__global__ __launch_bounds__(256) void head_kernel(
    const float* __restrict__ w3_0, const float* __restrict__ w3_1,
    const float* __restrict__ w3_2, float* out) {
  int wid = threadIdx.x >> 6, lane = threadIdx.x & 63;
  int r = blockIdx.x * 4 + wid;   // [0, 196608)
  int mlp = r >> 16;
  int row = r & 65535;
  const float* w3 = (mlp == 0) ? w3_0 : (mlp == 1) ? w3_1 : w3_2;
  const float* yp = out + (long)row * 774 + mlp * 258 + lane * 4;
  floatx2 ya = *(const floatx2*)yp;
  floatx2 yb = *(const floatx2*)(yp + 2);
  const float* wp = w3 + lane * 8;
  floatx4 wv0 = *(const floatx4*)wp;
  floatx4 wv1 = *(const floatx4*)(wp + 4);
  float s0 = ya[0] * wv0[0] + ya[1] * wv0[2] + yb[0] * wv1[0] + yb[1] * wv1[2];
  float s1 = ya[0] * wv0[1] + ya[1] * wv0[3] + yb[0] * wv1[1] + yb[1] * wv1[3];
#pragma unroll
  for (int off = 32; off > 0; off >>= 1) {
    s0 += __shfl_xor(s0, off, 64);
    s1 += __shfl_xor(s1, off, 64);
  }
  if (lane == 0) {
    float m = fmaxf(s0, s1);
    float e0 = __expf(s0 - m), e1 = __expf(s1 - m);
    float inv = 1.0f / (e0 + e1);
    floatx2 pr;
    pr[0] = e0 * inv;
    pr[1] = e1 * inv;
    *(floatx2*)(out + (long)row * 774 + mlp * 258 + 256) = pr;
  }
}

extern "C" void kernel_launch(void* const* d_in, const int* in_sizes, int n_in,
                              void* d_out, int out_size, void* d_ws, size_t ws_size,
                              hipStream_t stream) {
  const float* para = (const float*)d_in[0];
  const float* Wf1  = (const float*)d_in[1];
  const float* Wf2  = (const float*)d_in[2];
  const float* w3   = (const float*)d_in[3];
  const float* Wh1a = (const float*)d_in[4];
  const float* Wh1b = (const float*)d_in[5];
  const float* wl1  = (const float*)d_in[6];
  const float* Wh2a = (const float*)d_in[7];
  const float* Wh2b = (const float*)d_in[8];
  const float* wl2  = (const float*)d_in[9];

  float* uv = (float*)d_ws;                        // 4 MiB
  unsigned short* w2f =
      (unsigned short*)((char*)d_ws + (4u << 20)); // 1 MiB
  unsigned short* w1f =
      (unsigned short*)((char*)d_ws + (5u << 20)); // 4 MiB
  float* outp = (float*)d_out;                     // f32 [4*128*128][774]

  bool pair_ok   = ws_size >= (size_t)(5u << 20);
  bool stage1_ok = ws_size >= (size_t)(9u << 20);

  const float* W1s[3] = {Wf1, Wh1a, Wh2a};
  const float* W2s[3] = {Wf2, Wh1b, Wh2b};
  const float* w3s[3] = {w3, wl1, wl2};
  for (int mlp = 0; mlp < 3; mlp++) {
    if (stage1_ok) {
      prep_w1f<<<512, 256, 0, stream>>>(W1s[mlp], w1f);
      stage1_mfma<<<512, 256, 0, stream>>>(para, w1f, uv);
    } else {
      stage1_valu<<<256, 256, 0, stream>>>(para, W1s[mlp], uv);
    }
    if (pair_ok) {
      prep_w2<<<128, 256, 0, stream>>>(W2s[mlp], w2f);
      pair_mfma<<<512, 512, 0, stream>>>(uv, w2f, w3s[mlp], outp, mlp);
    } else {
      pair_valu<<<4096, 256, 0, stream>>>(uv, W2s[mlp], outp, mlp);
    }
  }
  if (!pair_ok) head_kernel<<<49152, 256, 0, stream>>>(w3, wl1, wl2, outp);
}